// Round 1
// baseline (9507.317 us; speedup 1.0000x reference)
//
#include <hip/hip_runtime.h>
#include <stdint.h>

#define T_STEPS 12
#define NN 20000
#define NE 320000
#define FIN 128
#define HD 256
#define FOUT 128

static __device__ __forceinline__ float sigmoidf_(float x) {
  return 1.0f / (1.0f + __expf(-x));
}

// ---------------- CSR build ----------------
__global__ void count_kernel(const int* __restrict__ dst, int* __restrict__ counts) {
  int e = blockIdx.x * blockDim.x + threadIdx.x;
  if (e < NE) atomicAdd(&counts[dst[e]], 1);
}

__global__ void scan_kernel(const int* __restrict__ counts, int* __restrict__ offs,
                            int* __restrict__ cursor) {
  __shared__ int sm[1024];
  __shared__ int carry_s;
  if (threadIdx.x == 0) carry_s = 0;
  __syncthreads();
  const int n = NN;
  int nch = (n + 1023) >> 10;
  for (int c = 0; c < nch; ++c) {
    int i = (c << 10) + (int)threadIdx.x;
    int v = (i < n) ? counts[i] : 0;
    sm[threadIdx.x] = v;
    __syncthreads();
    for (int off = 1; off < 1024; off <<= 1) {
      int t = (threadIdx.x >= (unsigned)off) ? sm[threadIdx.x - off] : 0;
      __syncthreads();
      sm[threadIdx.x] += t;
      __syncthreads();
    }
    int incl = sm[threadIdx.x];
    int carry_local = carry_s;
    if (i < n) {
      int excl = carry_local + incl - v;
      offs[i] = excl;
      cursor[i] = excl;
    }
    __syncthreads();
    if (threadIdx.x == 1023) carry_s = carry_local + incl;
    __syncthreads();
  }
  if (threadIdx.x == 0) offs[n] = carry_s;
}

__global__ void fill_kernel(const int* __restrict__ src, const int* __restrict__ dst,
                            int* __restrict__ cursor, int* __restrict__ esrc) {
  int e = blockIdx.x * blockDim.x + threadIdx.x;
  if (e < NE) {
    int d = dst[e];
    int pos = atomicAdd(&cursor[d], 1);
    esrc[pos] = src[e];
  }
}

// ---------------- segment-sum gather (CSR) ----------------
template <int W>
__global__ void agg_kernel(const float* __restrict__ feat, const int* __restrict__ offs,
                           const int* __restrict__ esrc, float* __restrict__ out) {
  int d = blockIdx.x;
  int f = threadIdx.x;
  int beg = offs[d], end = offs[d + 1];
  float acc0 = 0.f, acc1 = 0.f;
  int e = beg;
  for (; e + 1 < end; e += 2) {
    int s0 = esrc[e], s1 = esrc[e + 1];
    acc0 += feat[(size_t)s0 * W + f];
    acc1 += feat[(size_t)s1 * W + f];
  }
  if (e < end) acc0 += feat[(size_t)esrc[e] * W + f];
  out[(size_t)d * W + f] = acc0 + acc1;
}

// ---------------- fp32 GEMM: C[:, n0:n0+64] (+)= A @ B_gate + bias ----------------
// B is gate-blocked: element (k, global col n) lives at
//   B[(n>>8)*gateStride + k*ldb + (n&255)]
// bias indexed by global col. accumulate: C = C_old + A@B + bias, else A@B + bias.
__global__ __launch_bounds__(256) void gemm_kernel(
    const float* __restrict__ A, const float* __restrict__ B, float* __restrict__ C,
    const float* __restrict__ bias, int M, int K, int ldb, int gateStride, int ldc,
    int accumulate) {
  __shared__ float As[16][128];
  __shared__ float Bs[16][64];

  int tid = threadIdx.x;
  int tx = tid & 15;        // 0..15 -> col*4
  int ty = tid >> 4;        // 0..15 -> row*8
  int n0 = blockIdx.x * 64; // global col base
  int m0 = blockIdx.y * 128;

  int gate = n0 >> 8;
  const float* Bp = B + (size_t)gate * gateStride + (n0 & 255);

  float acc[8][4];
#pragma unroll
  for (int i = 0; i < 8; ++i)
#pragma unroll
    for (int j = 0; j < 4; ++j) acc[i][j] = 0.f;

  int r = tid >> 2;        // 0..63 (A stage row)
  int kc = (tid & 3) * 4;  // 0,4,8,12 (A stage k)
  int kr = tid >> 4;       // 0..15 (B stage k)
  int c4 = (tid & 15) * 4; // 0..60 (B stage col)

  for (int k0 = 0; k0 < K; k0 += 16) {
    int ar0 = m0 + r;
    int ar1 = m0 + r + 64;
    float4 av0 = make_float4(0.f, 0.f, 0.f, 0.f);
    float4 av1 = make_float4(0.f, 0.f, 0.f, 0.f);
    if (ar0 < M) av0 = *reinterpret_cast<const float4*>(&A[(size_t)ar0 * K + k0 + kc]);
    if (ar1 < M) av1 = *reinterpret_cast<const float4*>(&A[(size_t)ar1 * K + k0 + kc]);
    float4 bv = *reinterpret_cast<const float4*>(&Bp[(size_t)(k0 + kr) * ldb + c4]);

    __syncthreads();
    As[kc + 0][r] = av0.x;
    As[kc + 1][r] = av0.y;
    As[kc + 2][r] = av0.z;
    As[kc + 3][r] = av0.w;
    As[kc + 0][r + 64] = av1.x;
    As[kc + 1][r + 64] = av1.y;
    As[kc + 2][r + 64] = av1.z;
    As[kc + 3][r + 64] = av1.w;
    *reinterpret_cast<float4*>(&Bs[kr][c4]) = bv;
    __syncthreads();

#pragma unroll
    for (int kk = 0; kk < 16; ++kk) {
      float a[8], b[4];
      *reinterpret_cast<float4*>(&a[0]) = *reinterpret_cast<const float4*>(&As[kk][ty * 8]);
      *reinterpret_cast<float4*>(&a[4]) = *reinterpret_cast<const float4*>(&As[kk][ty * 8 + 4]);
      *reinterpret_cast<float4*>(&b[0]) = *reinterpret_cast<const float4*>(&Bs[kk][tx * 4]);
#pragma unroll
      for (int i = 0; i < 8; ++i)
#pragma unroll
        for (int j = 0; j < 4; ++j) acc[i][j] += a[i] * b[j];
    }
  }

  float4 bvec = *reinterpret_cast<const float4*>(&bias[n0 + tx * 4]);
#pragma unroll
  for (int i = 0; i < 8; ++i) {
    int row = m0 + ty * 8 + i;
    if (row >= M) continue;
    float* cp = &C[(size_t)row * ldc + n0 + tx * 4];
    float4 v;
    v.x = acc[i][0] + bvec.x;
    v.y = acc[i][1] + bvec.y;
    v.z = acc[i][2] + bvec.z;
    v.w = acc[i][3] + bvec.w;
    if (accumulate) {
      float4 o = *reinterpret_cast<const float4*>(cp);
      v.x += o.x; v.y += o.y; v.z += o.z; v.w += o.w;
    }
    *reinterpret_cast<float4*>(cp) = v;
  }
}

// ---------------- GRU elementwise ----------------
// xw layout: [N][768] = [r_pre | u_pre | c_pre_partial], all preactivations incl. biases
__global__ void eltwise_ru(const float* __restrict__ xw, const float* __restrict__ h,
                           float* __restrict__ ubuf, float* __restrict__ rh) {
  int idx4 = blockIdx.x * blockDim.x + threadIdx.x;
  if (idx4 >= NN * 64) return;
  int nrow = idx4 >> 6;
  int j4 = (idx4 & 63) << 2;
  const float* p = xw + (size_t)nrow * 768 + j4;
  float4 rpre = *reinterpret_cast<const float4*>(p);
  float4 upre = *reinterpret_cast<const float4*>(p + 256);
  float4 hv = *reinterpret_cast<const float4*>(h + (size_t)nrow * 256 + j4);
  float4 uu, rhv;
  uu.x = sigmoidf_(upre.x); uu.y = sigmoidf_(upre.y);
  uu.z = sigmoidf_(upre.z); uu.w = sigmoidf_(upre.w);
  rhv.x = sigmoidf_(rpre.x) * hv.x;
  rhv.y = sigmoidf_(rpre.y) * hv.y;
  rhv.z = sigmoidf_(rpre.z) * hv.z;
  rhv.w = sigmoidf_(rpre.w) * hv.w;
  *reinterpret_cast<float4*>(ubuf + (size_t)idx4 * 4) = uu;
  *reinterpret_cast<float4*>(rh + (size_t)idx4 * 4) = rhv;
}

__global__ void eltwise_c(const float* __restrict__ xw, const float* __restrict__ ubuf,
                          float* __restrict__ h) {
  int idx4 = blockIdx.x * blockDim.x + threadIdx.x;
  if (idx4 >= NN * 64) return;
  int nrow = idx4 >> 6;
  int j4 = (idx4 & 63) << 2;
  float4 cpre = *reinterpret_cast<const float4*>(xw + (size_t)nrow * 768 + 512 + j4);
  float4 uu = *reinterpret_cast<const float4*>(ubuf + (size_t)idx4 * 4);
  float* hp = h + (size_t)idx4 * 4;
  float4 hv = *reinterpret_cast<const float4*>(hp);
  float4 nh;
  nh.x = uu.x * hv.x + (1.f - uu.x) * tanhf(cpre.x);
  nh.y = uu.y * hv.y + (1.f - uu.y) * tanhf(cpre.y);
  nh.z = uu.z * hv.z + (1.f - uu.z) * tanhf(cpre.z);
  nh.w = uu.w * hv.w + (1.f - uu.w) * tanhf(cpre.w);
  *reinterpret_cast<float4*>(hp) = nh;
}

__global__ void copy_kernel(const float* __restrict__ in, float* __restrict__ out, int n4) {
  int i = blockIdx.x * blockDim.x + threadIdx.x;
  if (i < n4) reinterpret_cast<float4*>(out)[i] = reinterpret_cast<const float4*>(in)[i];
}

// ---------------- host ----------------
extern "C" void kernel_launch(void* const* d_in, const int* in_sizes, int n_in,
                              void* d_out, int out_size, void* d_ws, size_t ws_size,
                              hipStream_t stream) {
  const float* x   = (const float*)d_in[0];
  const float* h0  = (const float*)d_in[1];
  const int*   src = (const int*)d_in[2];
  const int*   dst = (const int*)d_in[3];
  const float* Wx0 = (const float*)d_in[4];
  const float* bx0 = (const float*)d_in[5];
  const float* Wh0 = (const float*)d_in[6];
  const float* bh0 = (const float*)d_in[7];
  const float* Wx1 = (const float*)d_in[8];
  const float* bx1 = (const float*)d_in[9];
  const float* Wh1 = (const float*)d_in[10];
  const float* bh1 = (const float*)d_in[11];
  const float* Wo  = (const float*)d_in[12];
  const float* bo  = (const float*)d_in[13];
  float* out = (float*)d_out;

  char* p = (char*)d_ws;
  int* offs   = (int*)p; p += (size_t)(NN + 1) * sizeof(int);
  int* cursor = (int*)p; p += (size_t)NN * sizeof(int);
  int* counts = (int*)p; p += (size_t)NN * sizeof(int);
  int* esrc   = (int*)p; p += (size_t)NE * sizeof(int);
  p = (char*)(((uintptr_t)p + 255) & ~(uintptr_t)255);
  float* xagg = (float*)p; p += (size_t)NN * FIN * sizeof(float);
  float* xw   = (float*)p; p += (size_t)NN * 768 * sizeof(float);
  float* hagg = (float*)p; p += (size_t)NN * HD * sizeof(float);
  float* rh   = (float*)p; p += (size_t)NN * HD * sizeof(float);
  float* ubuf = (float*)p; p += (size_t)NN * HD * sizeof(float);
  float* x1   = (float*)p; p += (size_t)NN * HD * sizeof(float);

  // GRU states live directly in d_out tail: [2, N, H] final states
  float* hc  = out + (size_t)T_STEPS * NN * FOUT;
  float* h0c = hc;
  float* h1c = hc + (size_t)NN * HD;

  // CSR build (per launch; deterministic up to fp-sum order)
  hipMemsetAsync(counts, 0, NN * sizeof(int), stream);
  count_kernel<<<(NE + 255) / 256, 256, 0, stream>>>(dst, counts);
  scan_kernel<<<1, 1024, 0, stream>>>(counts, offs, cursor);
  fill_kernel<<<(NE + 255) / 256, 256, 0, stream>>>(src, dst, cursor, esrc);

  // init h states from input
  copy_kernel<<<(2 * NN * HD / 4 + 255) / 256, 256, 0, stream>>>(h0, hc, 2 * NN * HD / 4);

  dim3 blk(256);
  int gy = (NN + 127) / 128;
  int ew_blocks = (NN * 64 + 255) / 256;

  for (int t = 0; t < T_STEPS; ++t) {
    const float* xt = x + (size_t)t * NN * FIN;

    // ---- layer 0 ----
    agg_kernel<FIN><<<NN, FIN, 0, stream>>>(xt, offs, esrc, xagg);
    gemm_kernel<<<dim3(768 / 64, gy), blk, 0, stream>>>(xagg, Wx0, xw, bx0, NN, FIN,
                                                        HD, FIN * HD, 768, 0);
    agg_kernel<HD><<<NN, HD, 0, stream>>>(h0c, offs, esrc, hagg);
    gemm_kernel<<<dim3(512 / 64, gy), blk, 0, stream>>>(hagg, Wh0, xw, bh0, NN, HD,
                                                        HD, HD * HD, 768, 1);
    eltwise_ru<<<ew_blocks, blk, 0, stream>>>(xw, h0c, ubuf, rh);
    agg_kernel<HD><<<NN, HD, 0, stream>>>(rh, offs, esrc, hagg);
    gemm_kernel<<<dim3(256 / 64, gy), blk, 0, stream>>>(hagg, Wh0 + 2 * HD * HD, xw + 512,
                                                        bh0 + 512, NN, HD, HD, 0, 768, 1);
    eltwise_c<<<ew_blocks, blk, 0, stream>>>(xw, ubuf, h0c);

    // ---- layer 1 ----
    agg_kernel<HD><<<NN, HD, 0, stream>>>(h0c, offs, esrc, x1);
    gemm_kernel<<<dim3(768 / 64, gy), blk, 0, stream>>>(x1, Wx1, xw, bx1, NN, HD,
                                                        HD, HD * HD, 768, 0);
    agg_kernel<HD><<<NN, HD, 0, stream>>>(h1c, offs, esrc, hagg);
    gemm_kernel<<<dim3(512 / 64, gy), blk, 0, stream>>>(hagg, Wh1, xw, bh1, NN, HD,
                                                        HD, HD * HD, 768, 1);
    eltwise_ru<<<ew_blocks, blk, 0, stream>>>(xw, h1c, ubuf, rh);
    agg_kernel<HD><<<NN, HD, 0, stream>>>(rh, offs, esrc, hagg);
    gemm_kernel<<<dim3(256 / 64, gy), blk, 0, stream>>>(hagg, Wh1 + 2 * HD * HD, xw + 512,
                                                        bh1 + 512, NN, HD, HD, 0, 768, 1);
    eltwise_c<<<ew_blocks, blk, 0, stream>>>(xw, ubuf, h1c);

    // ---- output projection ----
    gemm_kernel<<<dim3(128 / 64, gy), blk, 0, stream>>>(h1c, Wo, out + (size_t)t * NN * FOUT,
                                                        bo, NN, HD, FOUT, 0, FOUT, 0);
  }
}